// Round 10
// baseline (143.083 us; speedup 1.0000x reference)
//
#include <hip/hip_runtime.h>

#define N_NODES 50000
#define E_EDGES 600000
#define D_IN 128
#define O_OUT 128
#define R_REL 8
#define B_BAS 4
#define KTOT 640                  // 4 basis * 128 + self-loop 128
#define NSEG (N_NODES * R_REL)
#define NB1 98                    // ceil(50000/512): scan blocks == coarse buckets
#define YSTRIDE 512               // y row: 4 basis * 128
#define BM 64                     // nodes per gemm block

// prep kernel block ranges
#define NB_CONV 6250              // N*D/1024
#define NB_WT 320                 // 128*640/256
#define NB_DEG 2344               // ceil(E/256)

// binning
#define CHUNK_A 2048
#define NBA 293                   // ceil(600000/2048)

typedef __attribute__((ext_vector_type(8))) short bf16x8;
typedef __attribute__((ext_vector_type(4))) short bf16x4;
typedef __attribute__((ext_vector_type(4))) float f32x4;

static __device__ __forceinline__ unsigned short f2bf(float f) {
    unsigned int u = __float_as_uint(f);
    unsigned int r = (u + 0x7fffu + ((u >> 16) & 1u)) >> 16;
    return (unsigned short)r;
}
static __device__ __forceinline__ float bf2f(unsigned short b) {
    return __uint_as_float(((unsigned int)b) << 16);
}

// Fused: x->bf16 convert | Wt2 build | per-(dst,rel) degree count
__global__ __launch_bounds__(256) void prep_kernel(const float* __restrict__ x,
                                                   unsigned short* __restrict__ xb,
                                                   const float* __restrict__ basis_v,
                                                   const float* __restrict__ w_loop,
                                                   unsigned short* __restrict__ Wt2,
                                                   const int* __restrict__ dst,
                                                   const int* __restrict__ rel,
                                                   int* __restrict__ deg) {
    int b = blockIdx.x;
    if (b < NB_CONV) {
        int i = (b * 256 + threadIdx.x) * 4;
        float4 v = *(const float4*)&x[i];
        ushort4 o;
        o.x = f2bf(v.x); o.y = f2bf(v.y); o.z = f2bf(v.z); o.w = f2bf(v.w);
        *(ushort4*)&xb[i] = o;
    } else if (b < NB_CONV + NB_WT) {
        int i = (b - NB_CONV) * 256 + threadIdx.x;  // over 128*640
        int o = i / KTOT, j = i - o * KTOT;
        int bb = j >> 7, d = j & 127;
        float v = (bb < B_BAS) ? basis_v[((size_t)bb * D_IN + d) * O_OUT + o]
                               : w_loop[d * O_OUT + o];
        Wt2[i] = f2bf(v);
    } else {
        int e = (b - NB_CONV - NB_WT) * 256 + threadIdx.x;
        if (e < E_EDGES) atomicAdd(&deg[dst[e] * R_REL + rel[e]], 1);
    }
}

// Per-dst total count + block-local exclusive scan; emits invf too
__global__ __launch_bounds__(512) void scan1_kernel(const int* __restrict__ deg,
                                                    int* __restrict__ cntd,
                                                    float* __restrict__ invf,
                                                    int* __restrict__ exoff,
                                                    int* __restrict__ bsum) {
    __shared__ int s[512];
    int t = threadIdx.x, i = blockIdx.x * 512 + t;
    int c = 0;
    if (i < N_NODES) {
        #pragma unroll
        for (int r = 0; r < R_REL; ++r) {
            int dg = deg[i * R_REL + r];
            c += dg;
            invf[i * R_REL + r] = 1.0f / (float)max(dg, 1);
        }
        cntd[i] = c;
    }
    s[t] = c;
    __syncthreads();
    #pragma unroll
    for (int off = 1; off < 512; off <<= 1) {
        int add = (t >= off) ? s[t - off] : 0;
        __syncthreads();
        s[t] += add;
        __syncthreads();
    }
    if (i < N_NODES) exoff[i] = s[t] - c;
    if (t == 511) bsum[blockIdx.x] = s[511];
}

// Scan 98 block sums -> bbase[0..98] (with total at [98]); init cursor98 copy
__global__ __launch_bounds__(128) void scan2_kernel(const int* __restrict__ bsum,
                                                    int* __restrict__ bbase,
                                                    int* __restrict__ cursor98) {
    __shared__ int s[128];
    int t = threadIdx.x;
    int c = (t < NB1) ? bsum[t] : 0;
    s[t] = c;
    __syncthreads();
    #pragma unroll
    for (int off = 1; off < 128; off <<= 1) {
        int add = (t >= off) ? s[t - off] : 0;
        __syncthreads();
        s[t] += add;
        __syncthreads();
    }
    if (t < NB1) {
        int v = s[t] - c;
        bbase[t] = v;
        cursor98[t] = v;
    }
    if (t == NB1 - 1) bbase[NB1] = s[t];
}

// Pass A: bin edges into 98 coarse buckets (512 dsts each), block-contiguous runs.
// coarse payload: src(16) | rel(3)<<16 | dlow(9)<<19
__global__ __launch_bounds__(256) void binA_kernel(const int* __restrict__ src,
                                                   const int* __restrict__ dst,
                                                   const int* __restrict__ rel,
                                                   int* __restrict__ cursor98,
                                                   unsigned* __restrict__ coarse) {
    __shared__ int hist[NB1];
    __shared__ int base[NB1];
    int t = threadIdx.x;
    if (t < NB1) hist[t] = 0;
    __syncthreads();
    int e0 = blockIdx.x * CHUNK_A;
    for (int i = t; i < CHUNK_A; i += 256) {
        int e = e0 + i;
        if (e < E_EDGES) atomicAdd(&hist[dst[e] >> 9], 1);
    }
    __syncthreads();
    if (t < NB1) {
        int h = hist[t];
        base[t] = h ? atomicAdd(&cursor98[t], h) : 0;
        hist[t] = 0;
    }
    __syncthreads();
    for (int i = t; i < CHUNK_A; i += 256) {
        int e = e0 + i;
        if (e < E_EDGES) {
            int d = dst[e], b = d >> 9;
            int pos = base[b] + atomicAdd(&hist[b], 1);
            coarse[pos] = (unsigned)src[e] | ((unsigned)rel[e] << 16)
                        | ((unsigned)(d & 511) << 19);
        }
    }
}

// Pass B: one block per coarse bucket; exact per-dst slots via LDS counters.
__global__ __launch_bounds__(512) void binB_kernel(const unsigned* __restrict__ coarse,
                                                   const int* __restrict__ bbase,
                                                   const int* __restrict__ exoff,
                                                   unsigned* __restrict__ epack) {
    __shared__ int lcnt[512];
    int b = blockIdx.x, t = threadIdx.x;
    int d0 = b << 9;
    lcnt[t] = (d0 + t < N_NODES) ? exoff[d0 + t] : 0;
    __syncthreads();
    int s0 = bbase[b], s1 = bbase[b + 1];
    for (int i = s0 + t; i < s1; i += 512) {
        unsigned p = coarse[i];
        int dlow = (p >> 19) & 511;
        int pos = s0 + atomicAdd(&lcnt[dlow], 1);
        epack[pos] = p & 0x7ffffu;  // src | rel<<16
    }
}

// segagg: 32 lanes per dst node; 4-deep pipelined edge walk.
// y[d][b*128+..] = sum_edges coeffs[rel,b]*inv_deg*x_src
__global__ __launch_bounds__(256) void segagg_kernel(const unsigned short* __restrict__ xb,
                                                     const int* __restrict__ exoff,
                                                     const int* __restrict__ bbase,
                                                     const int* __restrict__ cntd,
                                                     const float* __restrict__ invf,
                                                     const unsigned* __restrict__ epack,
                                                     const float* __restrict__ coeffs,
                                                     unsigned short* __restrict__ y) {
    int d = blockIdx.x * 8 + (threadIdx.x >> 5);  // grid exact: 50000/8
    int l = threadIdx.x & 31;
    int beg = exoff[d] + bbase[d >> 9];
    int n = cntd[d];
    const unsigned* ep = epack + beg;
    float a0[4] = {}, a1[4] = {}, a2[4] = {}, a3[4] = {};
    int k = 0;
    for (; k + 4 <= n; k += 4) {
        unsigned p0 = ep[k], p1 = ep[k + 1], p2 = ep[k + 2], p3 = ep[k + 3];
        int s0 = p0 & 0xffffu, r0 = p0 >> 16;
        int s1 = p1 & 0xffffu, r1 = p1 >> 16;
        int s2 = p2 & 0xffffu, r2 = p2 >> 16;
        int s3 = p3 & 0xffffu, r3 = p3 >> 16;
        bf16x4 v0 = *(const bf16x4*)&xb[(size_t)s0 * D_IN + l * 4];
        bf16x4 v1 = *(const bf16x4*)&xb[(size_t)s1 * D_IN + l * 4];
        bf16x4 v2 = *(const bf16x4*)&xb[(size_t)s2 * D_IN + l * 4];
        bf16x4 v3 = *(const bf16x4*)&xb[(size_t)s3 * D_IN + l * 4];
        float i0 = invf[d * R_REL + r0];
        float i1 = invf[d * R_REL + r1];
        float i2 = invf[d * R_REL + r2];
        float i3 = invf[d * R_REL + r3];
        float4 cA = *(const float4*)&coeffs[r0 * B_BAS];
        float4 cB = *(const float4*)&coeffs[r1 * B_BAS];
        float4 cC = *(const float4*)&coeffs[r2 * B_BAS];
        float4 cD = *(const float4*)&coeffs[r3 * B_BAS];
        cA.x *= i0; cA.y *= i0; cA.z *= i0; cA.w *= i0;
        cB.x *= i1; cB.y *= i1; cB.z *= i1; cB.w *= i1;
        cC.x *= i2; cC.y *= i2; cC.z *= i2; cC.w *= i2;
        cD.x *= i3; cD.y *= i3; cD.z *= i3; cD.w *= i3;
        #pragma unroll
        for (int j = 0; j < 4; ++j) {
            float x0 = bf2f((unsigned short)v0[j]);
            float x1 = bf2f((unsigned short)v1[j]);
            float x2 = bf2f((unsigned short)v2[j]);
            float x3 = bf2f((unsigned short)v3[j]);
            a0[j] += cA.x * x0; a1[j] += cA.y * x0;
            a2[j] += cA.z * x0; a3[j] += cA.w * x0;
            a0[j] += cB.x * x1; a1[j] += cB.y * x1;
            a2[j] += cB.z * x1; a3[j] += cB.w * x1;
            a0[j] += cC.x * x2; a1[j] += cC.y * x2;
            a2[j] += cC.z * x2; a3[j] += cC.w * x2;
            a0[j] += cD.x * x3; a1[j] += cD.y * x3;
            a2[j] += cD.z * x3; a3[j] += cD.w * x3;
        }
    }
    for (; k < n; ++k) {
        unsigned p0 = ep[k];
        int s0 = p0 & 0xffffu, r0 = p0 >> 16;
        bf16x4 v0 = *(const bf16x4*)&xb[(size_t)s0 * D_IN + l * 4];
        float i0 = invf[d * R_REL + r0];
        float4 cA = *(const float4*)&coeffs[r0 * B_BAS];
        cA.x *= i0; cA.y *= i0; cA.z *= i0; cA.w *= i0;
        #pragma unroll
        for (int j = 0; j < 4; ++j) {
            float x0 = bf2f((unsigned short)v0[j]);
            a0[j] += cA.x * x0; a1[j] += cA.y * x0;
            a2[j] += cA.z * x0; a3[j] += cA.w * x0;
        }
    }
    size_t base = (size_t)d * YSTRIDE + l * 4;
    #pragma unroll
    for (int b = 0; b < 4; ++b) {
        const float* ab = (b == 0) ? a0 : (b == 1) ? a1 : (b == 2) ? a2 : a3;
        ushort4 o;
        o.x = f2bf(ab[0]); o.y = f2bf(ab[1]); o.z = f2bf(ab[2]); o.w = f2bf(ab[3]);
        *(ushort4*)&y[base + b * 128] = o;
    }
}

// gemm2: out = relu([y | xb] @ [Vstack; w_loop] + bias), K=640.
// LDS double-buffered A (one barrier per chunk); B direct from L2-resident Wt2.
__global__ __launch_bounds__(256) void gemm2_kernel(const unsigned short* __restrict__ y,
                                                    const unsigned short* __restrict__ xb,
                                                    const unsigned short* __restrict__ Wt2,
                                                    const float* __restrict__ bias,
                                                    float* __restrict__ out) {
    __shared__ short As[2][BM * 136];   // 2 x 17.4 KB
    const int node0 = blockIdx.x * BM;
    const int t = threadIdx.x;
    const int w = t >> 6, l = t & 63;
    const int lr = l & 15, lg = l >> 4;
    const int brow = w * 32;
    const int rw = t >> 2, c16 = (t & 3) * 4;   // staging coords: 4 int4/thread

    f32x4 acc[4][2] = {};

    // stage chunk 0
    {
        const unsigned short* Asrc = y + (size_t)node0 * YSTRIDE;
        #pragma unroll
        for (int i = 0; i < 4; ++i) {
            int4 v = make_int4(0, 0, 0, 0);
            if (node0 + rw < N_NODES)
                v = *(const int4*)&Asrc[(size_t)rw * YSTRIDE + (c16 + i) * 8];
            *(int4*)&As[0][rw * 136 + (c16 + i) * 8] = v;
        }
    }
    __syncthreads();

    for (int r = 0; r < 5; ++r) {
        const int cur = r & 1;
        int4 pre[4];
        if (r < 4) {  // prefetch chunk r+1 into regs (overlaps MFMA below)
            const unsigned short* Asrc;
            int astride;
            if (r + 1 < B_BAS) { Asrc = y + (size_t)node0 * YSTRIDE + (r + 1) * 128; astride = YSTRIDE; }
            else               { Asrc = xb + (size_t)node0 * D_IN;                   astride = D_IN;   }
            #pragma unroll
            for (int i = 0; i < 4; ++i) {
                pre[i] = make_int4(0, 0, 0, 0);
                if (node0 + rw < N_NODES)
                    pre[i] = *(const int4*)&Asrc[(size_t)rw * astride + (c16 + i) * 8];
            }
        }
        #pragma unroll
        for (int ks = 0; ks < 4; ++ks) {
            int kb = ks * 32 + lg * 8;
            bf16x8 af[4];
            #pragma unroll
            for (int mf = 0; mf < 4; ++mf)
                af[mf] = *(const bf16x8*)&As[cur][(mf * 16 + lr) * 136 + kb];
            #pragma unroll
            for (int jn = 0; jn < 2; ++jn) {
                bf16x8 bfr = *(const bf16x8*)&Wt2[(size_t)(brow + jn * 16 + lr) * KTOT + r * 128 + kb];
                #pragma unroll
                for (int mf = 0; mf < 4; ++mf)
                    acc[mf][jn] = __builtin_amdgcn_mfma_f32_16x16x32_bf16(af[mf], bfr, acc[mf][jn], 0, 0, 0);
            }
        }
        if (r < 4) {
            #pragma unroll
            for (int i = 0; i < 4; ++i)
                *(int4*)&As[cur ^ 1][rw * 136 + (c16 + i) * 8] = pre[i];
        }
        __syncthreads();
    }

    // epilogue: C/D layout col=lane&15, row=(lane>>4)*4+i  [m89-verified]
    #pragma unroll
    for (int jn = 0; jn < 2; ++jn) {
        int col = brow + jn * 16 + lr;
        float bv = bias[col];
        #pragma unroll
        for (int mf = 0; mf < 4; ++mf) {
            #pragma unroll
            for (int i2 = 0; i2 < 4; ++i2) {
                int row = node0 + mf * 16 + lg * 4 + i2;
                if (row < N_NODES)
                    out[(size_t)row * O_OUT + col] = fmaxf(acc[mf][jn][i2] + bv, 0.f);
            }
        }
    }
}

extern "C" void kernel_launch(void* const* d_in, const int* in_sizes, int n_in,
                              void* d_out, int out_size, void* d_ws, size_t ws_size,
                              hipStream_t stream) {
    (void)in_sizes; (void)n_in; (void)out_size; (void)ws_size;
    const float* x       = (const float*)d_in[0];
    const float* basis_v = (const float*)d_in[1];
    const float* coeffs  = (const float*)d_in[2];
    const float* w_loop  = (const float*)d_in[3];
    const float* bias_p  = (const float*)d_in[4];
    const int*   src     = (const int*)d_in[5];
    const int*   dst     = (const int*)d_in[6];
    const int*   rel     = (const int*)d_in[7];
    float* out = (float*)d_out;

    char* ws = (char*)d_ws;
    unsigned short* Wt2      = (unsigned short*)(ws);             //     163,840 B
    unsigned short* xb       = (unsigned short*)(ws + 163840);    //  12,800,000 B
    int*            deg      = (int*)(ws + 12963840);             //   1,600,000 B
    float*          invf     = (float*)(ws + 14563840);           //   1,600,000 B
    int*            cntd     = (int*)(ws + 16163840);             //     200,000 B
    int*            exoff    = (int*)(ws + 16363840);             //     200,000 B
    int*            bsum     = (int*)(ws + 16563840);             //       1,024 B
    int*            bbase    = (int*)(ws + 16564864);             //       1,024 B (99 ints)
    int*            cursor98 = (int*)(ws + 16565888);             //       1,024 B
    unsigned*       coarse   = (unsigned*)(ws + 16566912);        //   2,400,000 B
    unsigned*       epack    = (unsigned*)(ws + 18966912);        //   2,400,000 B
    unsigned short* y        = (unsigned short*)(ws + 21366912);  //  51,200,000 B

    hipMemsetAsync(deg, 0, (size_t)NSEG * sizeof(int), stream);

    prep_kernel<<<NB_CONV + NB_WT + NB_DEG, 256, 0, stream>>>(x, xb, basis_v, w_loop, Wt2,
                                                              dst, rel, deg);
    scan1_kernel<<<NB1, 512, 0, stream>>>(deg, cntd, invf, exoff, bsum);
    scan2_kernel<<<1, 128, 0, stream>>>(bsum, bbase, cursor98);
    binA_kernel<<<NBA, 256, 0, stream>>>(src, dst, rel, cursor98, coarse);
    binB_kernel<<<NB1, 512, 0, stream>>>(coarse, bbase, exoff, epack);
    segagg_kernel<<<N_NODES / 8, 256, 0, stream>>>(xb, exoff, bbase, cntd, invf, epack,
                                                   coeffs, y);
    gemm2_kernel<<<(N_NODES + BM - 1) / BM, 256, 0, stream>>>(y, xb, Wt2, bias_p, out);
}